// Round 9
// baseline (189.447 us; speedup 1.0000x reference)
//
#include <hip/hip_runtime.h>
#include <stdint.h>

// LinearAttention on MI355X — round 13: swapped-operand MFMA epilogues.
//  R12 post-mortem: k1's 46.5µs is VALU-bound (32.5% VALUBusy) on the scalar
//  f2bf + 2B-store epilogue (C/D frag = 4 rows x 1 col per thread).
//  Swapping mfma operand order (legal: A/B frags have identical lane layouts)
//  transposes the mapping: thread holds 4 CONTIGUOUS cols -> float4 / cvt_pk
//  + ushort4 stores. 64 scalar stores -> 16 vector stores, ~500 -> ~110 VALU.
//  Everything else identical to R12 (passed, 184.5µs).
//
// final_b = N_b · x_b + bias;  N_b = (W_out ⊙ ctx_b) · W_q;
// ctx_b[h] = (1/rowsum) · exp(K)·V^T  (exp w/o max-subtraction: K~N(0,0.64), safe).
//
// ws layout (bytes):
//   xbT    bf16 [8][4096][256]     @ 0          (16,777,216)
//   wkvb   bf16 [1024][256]        @ 16777216   (   524,288)
//   woutb  bf16 [256][512]         @ 17301504   (   262,144)
//   wqT    bf16 [256][512]         @ 17563648   (   262,144)
//   ctxp   f32  [8][32][128][128]  @ 17825792   (16,777,216)  split-8 partials
//   rowsum f32  [8][512]           @ 34603008   (    16,384)  atomic accum
//   ctxb   bf16 [32][128][128]     @ 34619392   ( 1,048,576)
//   Mb     bf16 [8][256][512]      @ 35667968   ( 2,097,152)
//   Nb     bf16 [8][256][256]      @ 37765120   ( 1,048,576)
//   kv     bf16 [8][1024][4096]    @ 38813696   (67,108,864)  K part = exp(K)
// total 105,922,560 B

using frag8 = __attribute__((ext_vector_type(8))) short;   // 8 x bf16
using f32x4 = __attribute__((ext_vector_type(4))) float;

__device__ __forceinline__ unsigned short f2bf(float f) {
    union { float f; unsigned int u; } c; c.f = f;
    unsigned int u = c.u;
    return (unsigned short)((u + 0x7FFFu + ((u >> 16) & 1u)) >> 16);
}

// pack 4 f32 -> 4 bf16 (RNE, same as f2bf) and store as one 8B write
__device__ __forceinline__ void store_bf16x4(unsigned short* p, f32x4 v) {
    float v0 = v[0], v1 = v[1], v2 = v[2], v3 = v[3];
    uint2 o;
    asm("v_cvt_pk_bf16_f32 %0, %1, %2" : "=v"(o.x) : "v"(v0), "v"(v1));
    asm("v_cvt_pk_bf16_f32 %0, %1, %2" : "=v"(o.y) : "v"(v2), "v"(v3));
    *(uint2*)p = o;
}

__device__ __forceinline__ void gl_lds16(const void* g, void* l) {
    __builtin_amdgcn_global_load_lds(
        (const __attribute__((address_space(1))) unsigned int*)g,
        (__attribute__((address_space(3))) unsigned int*)l, 16, 0, 0);
}

// ------- k0_prep: xbT transpose (blk<2048) + weight prep (blk>=2048) -------
__global__ __launch_bounds__(256) void k0_prep(
    const float* __restrict__ x, const float* __restrict__ w_qkv,
    const float* __restrict__ w_out,
    unsigned short* __restrict__ xbT, unsigned short* __restrict__ wkvb,
    unsigned short* __restrict__ woutb, unsigned short* __restrict__ wqT)
{
    __shared__ float T[64][65];
    const int tid = threadIdx.x;
    const int blk0 = blockIdx.x;
    if (blk0 < 2048) {               // xbT[b][n][c] = bf16(x[b][c][n])
        const int n0 = (blk0 & 63) * 64, c0 = ((blk0 >> 6) & 3) * 64, b = blk0 >> 8;
        const float* xb = x + (size_t)b * 1048576;
        const int cr = tid >> 4, nc = (tid & 15) * 4;
        #pragma unroll
        for (int p = 0; p < 4; ++p) {
            float4 v = *(const float4*)(xb + (size_t)(c0 + cr + p * 16) * 4096 + n0 + nc);
            T[cr + p * 16][nc + 0] = v.x; T[cr + p * 16][nc + 1] = v.y;
            T[cr + p * 16][nc + 2] = v.z; T[cr + p * 16][nc + 3] = v.w;
        }
        __syncthreads();
        const int n = tid >> 2, cc = (tid & 3) * 16;
        unsigned short* dst = xbT + (size_t)b * 1048576 + (size_t)(n0 + n) * 256 + c0 + cc;
        #pragma unroll
        for (int g = 0; g < 4; ++g) {
            ushort4 o;
            o.x = f2bf(T[cc + g * 4 + 0][n]);
            o.y = f2bf(T[cc + g * 4 + 1][n]);
            o.z = f2bf(T[cc + g * 4 + 2][n]);
            o.w = f2bf(T[cc + g * 4 + 3][n]);
            *(ushort4*)(dst + g * 4) = o;
        }
        return;
    }
    const int blk = blk0 - 2048;
    if (blk < 256) {                 // wkvb: w_qkv rows 512..1536 -> bf16
        const int idx = (blk * 256 + tid) * 4;
        float4 v = *(const float4*)(w_qkv + 512 * 256 + idx);
        ushort4 o;
        o.x = f2bf(v.x); o.y = f2bf(v.y); o.z = f2bf(v.z); o.w = f2bf(v.w);
        *(ushort4*)(wkvb + idx) = o;
    } else if (blk < 384) {          // woutb: w_out -> bf16
        const int idx = ((blk - 256) * 256 + tid) * 4;
        float4 v = *(const float4*)(w_out + idx);
        ushort4 o;
        o.x = f2bf(v.x); o.y = f2bf(v.y); o.z = f2bf(v.z); o.w = f2bf(v.w);
        *(ushort4*)(woutb + idx) = o;
    } else {                         // wqT[c][j] = bf16(w_qkv[j][c]), j<512
        const int t = blk - 384;     // 32 tiles: 8 j-tiles x 4 c-tiles
        const int j0 = (t >> 2) * 64, c0 = (t & 3) * 64;
        const int r = tid >> 4, cc = (tid & 15) * 4;
        #pragma unroll
        for (int p = 0; p < 4; ++p) {
            float4 v = *(const float4*)(w_qkv + (j0 + r + p * 16) * 256 + c0 + cc);
            T[r + p * 16][cc + 0] = v.x; T[r + p * 16][cc + 1] = v.y;
            T[r + p * 16][cc + 2] = v.z; T[r + p * 16][cc + 3] = v.w;
        }
        __syncthreads();
        const int c = tid >> 2, jj = (tid & 3) * 16;
        #pragma unroll
        for (int g = 0; g < 4; ++g) {
            ushort4 o;
            o.x = f2bf(T[jj + g * 4 + 0][c]);
            o.y = f2bf(T[jj + g * 4 + 1][c]);
            o.z = f2bf(T[jj + g * 4 + 2][c]);
            o.w = f2bf(T[jj + g * 4 + 3][c]);
            *(ushort4*)(wqT + (c0 + c) * 512 + j0 + jj + g * 4) = o;
        }
    }
}

// -------- MFMA gemm_bt: C[m][n] = sum_k A[m][k] * B[n][k]  (bf16 in) -------
// 128x128 block tile, BK=32, 4 waves (each 64x64), 16x16x32 bf16 MFMA.
// Simple full-drain 2-phase loop (proven fastest @2048 blocks).
// Staging XOR involution swizzle: source k-slot ^= (row>>1)&3 (both sides).
// SWAPPED operand order: mfma(b,a) -> thread holds C[wm+mt*16+l16]
// [wn+nt*16+quad*4 .. +3] = 4 contiguous cols -> vector stores.
// MODE 0: C bf16, z-strided (k5: N).
// MODE 1: C f32 + bias[row] (k6: out).
// MODE 2: k3 ctxp — k-slice = blockIdx.x*512, plain f32x4 stores (NO atomics).
// MODE 3: k4 M — A=woutb col-block h, B=ctxb[bh], C=Mb col-block h, bf16.
// MODE 4: k1 kv — blockIdx.y<4 (K rows): exp(acc) + rowsum atomics.
template<int MODE>
__global__ __launch_bounds__(256) void mfma_bt(
    const unsigned short* __restrict__ A0, int lda,
    const unsigned short* __restrict__ B0, int ldb,
    void* __restrict__ C0, int ldc,
    const float* __restrict__ bias, int Kp,
    unsigned long long sAz, unsigned long long sBz, unsigned long long sCz)
{
    __shared__ unsigned short As[128 * 32];
    __shared__ unsigned short Bs[128 * 32];
    const int tid  = threadIdx.x;
    const int w    = tid >> 6, lane = tid & 63;
    const int quad = lane >> 4, l16 = lane & 15;
    const int wm = (w >> 1) * 64, wn = (w & 1) * 64;
    const int z = blockIdx.z;

    const unsigned short* A;
    const unsigned short* B;
    int m0, n0, ks, NS;
    if constexpr (MODE == 2) {
        m0 = 0; n0 = 0;
        ks = blockIdx.x * 512; NS = 16;
        const unsigned long long off =
            ((unsigned long long)(z >> 2) * 1024ull + (unsigned long long)(z & 3) * 128ull) * 4096ull;
        A = A0 + off; B = B0 + off;
    } else if constexpr (MODE == 3) {
        m0 = blockIdx.y * 128; n0 = 0;
        ks = 0; NS = Kp >> 5;   // 4
        A = A0 + (unsigned long long)(z & 3) * 128ull + (unsigned long long)m0 * lda;
        B = B0 + (unsigned long long)z * 16384ull;
    } else {
        m0 = blockIdx.y * 128; n0 = blockIdx.x * 128;
        ks = 0; NS = Kp >> 5;
        A = A0 + sAz * z + (unsigned long long)m0 * lda;
        B = B0 + sBz * z + (unsigned long long)n0 * ldb;
    }

    // staging: 512 chunks of 16B per tile; chunk c -> LDS row c>>2, slot c&3;
    // source slot pre-swizzled (involution, verified R3-R8)
    const int c0 = w * 128 + lane, c1 = c0 + 64;
    const int r0 = c0 >> 2, s0 = ((c0 & 3) ^ ((r0 >> 1) & 3)) * 8;
    const int r1 = c1 >> 2, s1 = ((c1 & 3) ^ ((r1 >> 1) & 3)) * 8;
    const unsigned short* gA0 = A + (unsigned long long)r0 * lda + s0 + ks;
    const unsigned short* gA1 = A + (unsigned long long)r1 * lda + s1 + ks;
    const unsigned short* gB0 = B + (unsigned long long)r0 * ldb + s0 + ks;
    const unsigned short* gB1 = B + (unsigned long long)r1 * ldb + s1 + ks;
    unsigned short* lA0 = As + w * 1024;
    unsigned short* lA1 = As + w * 1024 + 512;
    unsigned short* lB0 = Bs + w * 1024;
    unsigned short* lB1 = Bs + w * 1024 + 512;

    f32x4 acc[4][4] = {};

    for (int t = 0; t < NS; ++t) {
        const int k0 = t * 32;
        gl_lds16(gA0 + k0, lA0);
        gl_lds16(gA1 + k0, lA1);
        gl_lds16(gB0 + k0, lB0);
        gl_lds16(gB1 + k0, lB1);
        __syncthreads();
        frag8 a[4], b[4];
        #pragma unroll
        for (int tt = 0; tt < 4; ++tt) {
            const int ra = wm + tt * 16 + l16;
            const int rb = wn + tt * 16 + l16;
            a[tt] = *(const frag8*)(As + ra * 32 + ((quad ^ ((ra >> 1) & 3)) << 3));
            b[tt] = *(const frag8*)(Bs + rb * 32 + ((quad ^ ((rb >> 1) & 3)) << 3));
        }
        // swapped operand order: D[i][j], i = B-row (n-dim), j = A-row (m-dim)
        #pragma unroll
        for (int mt = 0; mt < 4; ++mt)
            #pragma unroll
            for (int nt = 0; nt < 4; ++nt)
                acc[mt][nt] = __builtin_amdgcn_mfma_f32_16x16x32_bf16(
                    b[nt], a[mt], acc[mt][nt], 0, 0, 0);
        __syncthreads();
    }

    // epilogue (swapped mapping): acc[mt][nt][r] = C[wm+mt*16+l16][wn+nt*16+quad*4+r]
    if constexpr (MODE == 0 || MODE == 3) {
        unsigned short* C;
        if constexpr (MODE == 0)
            C = (unsigned short*)C0 + sCz * z + (unsigned long long)m0 * ldc + n0;
        else
            C = (unsigned short*)C0 + (unsigned long long)(z >> 2) * 131072ull
              + (unsigned long long)(z & 3) * 128ull + (unsigned long long)m0 * ldc;
        #pragma unroll
        for (int mt = 0; mt < 4; ++mt) {
            const int row = wm + mt * 16 + l16;
            #pragma unroll
            for (int nt = 0; nt < 4; ++nt) {
                const int col = wn + nt * 16 + quad * 4;
                store_bf16x4(C + (unsigned long long)row * ldc + col, acc[mt][nt]);
            }
        }
    } else if constexpr (MODE == 4) {
        unsigned short* C = (unsigned short*)C0 + sCz * z + (unsigned long long)m0 * ldc + n0;
        if (blockIdx.y < 4) {
            // K rows: write exp(acc), per-row sums -> atomic rowsum
            float* rs = (float*)bias;   // rowsum base, f32 [8][512]
            #pragma unroll
            for (int mt = 0; mt < 4; ++mt) {
                const int row = wm + mt * 16 + l16;
                float rsum = 0.f;
                #pragma unroll
                for (int nt = 0; nt < 4; ++nt) {
                    const int col = wn + nt * 16 + quad * 4;
                    f32x4 e;
                    #pragma unroll
                    for (int r = 0; r < 4; ++r) {
                        e[r] = __expf(acc[mt][nt][r]);
                        rsum += e[r];
                    }
                    store_bf16x4(C + (unsigned long long)row * ldc + col, e);
                }
                // reduce over quads (lanes sharing the same row differ in quad)
                rsum += __shfl_xor(rsum, 16, 64);
                rsum += __shfl_xor(rsum, 32, 64);
                if (quad == 0)
                    atomicAdd(rs + (unsigned long long)z * 512 + m0 + row, rsum);
            }
        } else {
            // V rows: plain vectorized bf16 write
            #pragma unroll
            for (int mt = 0; mt < 4; ++mt) {
                const int row = wm + mt * 16 + l16;
                #pragma unroll
                for (int nt = 0; nt < 4; ++nt) {
                    const int col = wn + nt * 16 + quad * 4;
                    store_bf16x4(C + (unsigned long long)row * ldc + col, acc[mt][nt]);
                }
            }
        }
    } else if constexpr (MODE == 1) {
        float* C = (float*)C0 + sCz * z + (unsigned long long)m0 * ldc + n0;
        #pragma unroll
        for (int mt = 0; mt < 4; ++mt) {
            const int row = wm + mt * 16 + l16;
            const float bv = bias[m0 + row];
            #pragma unroll
            for (int nt = 0; nt < 4; ++nt) {
                const int col = wn + nt * 16 + quad * 4;
                f32x4 t = acc[mt][nt];
                t[0] += bv; t[1] += bv; t[2] += bv; t[3] += bv;
                *(f32x4*)(C + (unsigned long long)row * ldc + col) = t;
            }
        }
    } else {
        // MODE 2: plain f32x4 stores into ctxp[slice] — NO atomics
        float* C = (float*)C0 + ((unsigned long long)blockIdx.x * 32 + z) * 16384ull;
        #pragma unroll
        for (int mt = 0; mt < 4; ++mt) {
            const int row = wm + mt * 16 + l16;
            #pragma unroll
            for (int nt = 0; nt < 4; ++nt) {
                const int col = wn + nt * 16 + quad * 4;
                *(f32x4*)(C + row * 128 + col) = acc[mt][nt];
            }
        }
    }
}

// -- k3_sumscale: ctxb[bh][d][e] = bf16( (sum_s ctxp[s][bh][d][e]) / rowsum ) --
__global__ __launch_bounds__(256) void k3_sumscale(
    const float* __restrict__ ctxp, const float* __restrict__ rowsum,
    unsigned short* __restrict__ ctxb)
{
    const int idx = (blockIdx.x * 256 + threadIdx.x) * 4;   // element index
    float4 s = make_float4(0.f, 0.f, 0.f, 0.f);
    #pragma unroll
    for (int sl = 0; sl < 8; ++sl) {
        float4 t = *(const float4*)(ctxp + (size_t)sl * 524288 + idx);
        s.x += t.x; s.y += t.y; s.z += t.z; s.w += t.w;
    }
    const float inv = 1.0f / rowsum[idx >> 7];              // row = bh*128+d
    ushort4 o;
    o.x = f2bf(s.x * inv); o.y = f2bf(s.y * inv);
    o.z = f2bf(s.z * inv); o.w = f2bf(s.w * inv);
    *(ushort4*)(ctxb + idx) = o;
}

extern "C" void kernel_launch(void* const* d_in, const int* in_sizes, int n_in,
                              void* d_out, int out_size, void* d_ws, size_t ws_size,
                              hipStream_t stream) {
    (void)in_sizes; (void)n_in; (void)out_size; (void)ws_size;
    const float* x     = (const float*)d_in[0];  // f32 [8,256,64,64]
    const float* w_qkv = (const float*)d_in[1];  // f32 [1536,256]
    const float* w_out = (const float*)d_in[2];  // f32 [256,512]
    const float* b_out = (const float*)d_in[3];  // f32 [256]
    float* out = (float*)d_out;                  // f32 [8,256,64,64]

    char* ws = (char*)d_ws;
    unsigned short* xbT    = (unsigned short*)ws;                 // 16,777,216
    unsigned short* wkvb   = (unsigned short*)(ws + 16777216);    //    524,288
    unsigned short* woutb  = (unsigned short*)(ws + 17301504);    //    262,144
    unsigned short* wqT    = (unsigned short*)(ws + 17563648);    //    262,144
    float*          ctxp   = (float*)(ws + 17825792);             // 16,777,216
    float*          rowsum = (float*)(ws + 34603008);             //     16,384
    unsigned short* ctxb   = (unsigned short*)(ws + 34619392);    //  1,048,576
    unsigned short* Mb     = (unsigned short*)(ws + 35667968);    //  2,097,152
    unsigned short* Nb     = (unsigned short*)(ws + 37765120);    //  1,048,576
    unsigned short* kv     = (unsigned short*)(ws + 38813696);    // 67,108,864

    // zero rowsum only (16 KB — ctxp uses plain stores, no zeroing needed)
    hipMemsetAsync(ws + 34603008, 0, 16384, stream);

    k0_prep<<<dim3(2464), 256, 0, stream>>>(x, w_qkv, w_out, xbT, wkvb, woutb, wqT);
    // k1: kv[b,r,n] = sum_c wkvb[r,c]*xbT[b,n,c]; K rows stored as exp + rowsum
    mfma_bt<4><<<dim3(32, 8, 8), 256, 0, stream>>>(
        wkvb, 256, xbT, 256, kv, 4096, rowsum, 256,
        0ull, 1048576ull, 4194304ull);
    // k3: ctxp[s,bh,d,e] = sum_{n in slice s} expK[d,n]*V[e,n]  (plain stores)
    mfma_bt<2><<<dim3(8, 1, 32), 256, 0, stream>>>(
        kv, 4096, kv + (size_t)512 * 4096, 4096, ctxp, 128, nullptr, 0,
        0ull, 0ull, 0ull);
    // sum 8 slices + apply 1/rowsum -> ctxb bf16
    k3_sumscale<<<dim3(512), 256, 0, stream>>>(ctxp, rowsum, ctxb);
    // k4: Mb[b][o][h*128+d] = sum_e woutb[o][h*128+e] * ctxb[bh][d][e]
    mfma_bt<3><<<dim3(1, 2, 32), 256, 0, stream>>>(
        woutb, 512, ctxb, 128, Mb, 512, nullptr, 128,
        0ull, 0ull, 0ull);
    // k5: Nb[b][o][c] = sum_j Mb[b][o][j] * wqT[c][j]
    mfma_bt<0><<<dim3(2, 2, 8), 256, 0, stream>>>(
        Mb, 512, wqT, 512, Nb, 256, nullptr, 512,
        131072ull, 0ull, 65536ull);
    // k6: out[b,o,n] = sum_c Nb[b,o,c] * xbT[b,n,c] + b_out[o]
    mfma_bt<1><<<dim3(32, 2, 8), 256, 0, stream>>>(
        Nb, 256, xbT, 256, out, 4096, b_out, 256,
        65536ull, 1048576ull, 1048576ull);
}